// Round 5
// baseline (428.017 us; speedup 1.0000x reference)
//
#include <hip/hip_runtime.h>

// ---------------------------------------------------------------------------
// BeliefStateWrapper: gather(fi,bi) -> Linear(1024->512)+LeakyReLU ->
// Linear(512->64000) -> per-branch log_softmax NLL -> weighted mean (scalar).
//
// R13 == R12 resubmitted (previous round was an infra container failure,
// not a kernel verdict; code audited for hang/OOB risks, none found).
//
// R12: W=128 strips at FULL occupancy. Resource model (R8/R11 counters):
// gemm2 ~ sum of MFMA 69us + B-LDS 40us + A-L2 (strips x 2.69MB) + W2-HBM
// 21us, poorly overlapped. R11 halved A-L2 but died on occupancy (128KB LDS
// -> 1 block -> 2 waves/SIMD). R12: 1024-thread block, 16 waves, wave =
// R4/R8-VERBATIM 64-col x 1-panel schedule (64 AGPR + 64 VGPR -> 4
// waves/SIMD); wave w owns col-half (w&1) of the 128-col strip and panel
// slot (w>>1). A-L2 halves (500 blocks x 2.69MB = 1.35GB), sibling
// col-half waves share A via L1, LDS/occupancy match R8. Partial rows =
// 2*strip+h (1000 rows, final_kernel unchanged).
// ---------------------------------------------------------------------------

typedef __bf16 bf16x8 __attribute__((ext_vector_type(8)));
typedef __bf16 bf16x4 __attribute__((ext_vector_type(4)));
typedef float f32x4  __attribute__((ext_vector_type(4)));

#define MFMA16(a, b, c) __builtin_amdgcn_mfma_f32_16x16x32_bf16(a, b, c, 0, 0, 0)

static constexpr int Bsz   = 2;
static constexpr int L     = 512;
static constexpr int D     = 512;
static constexpr int V     = 32000;
static constexpr int K1    = 2 * D;      // 1024
static constexpr int N1    = D;          // 512
static constexpr int K2    = D;          // 512
static constexpr int N2    = 2 * V;      // 64000
static constexpr int SW    = 128;        // strip width (gemm2 columns/block)
static constexpr int NSTRIP = N2 / SW;   // 500 blocks
static constexpr int NPART  = NSTRIP * 2;// 1000 partial rows (strip x col-half)

// Apack chunk base (bf16 elems) for (panel, ks, mi); chunk = 64 lanes x 8
// bf16 = 512 elems = 1 KB. Lane l holds A[panel*64+mi*16+(l&15)]
// [ks*32+(l>>4)*8 .. +7].
__device__ __host__ inline size_t apack_chunk(int panel, int ks, int mi) {
    return (((size_t)panel * 16 + ks) * 4 + mi) * 512;
}

// ---------------------------------------------------------------------------
// prep kernel: blocks [0, G1) do gather+cast (+labcol side-task, interleaved
// labcol[m*2+br] layout); blocks [G1, G1+128) transpose+cast w1 -> W1T.
// ---------------------------------------------------------------------------
__global__ void prep_kernel(const float* __restrict__ fwd,
                            const float* __restrict__ bwd,
                            const int* __restrict__ fi,
                            const int* __restrict__ bi,
                            const int* __restrict__ seq,
                            const float* __restrict__ w1,
                            __bf16* __restrict__ A1,
                            __bf16* __restrict__ W1T,
                            int* __restrict__ labcol,
                            int N, int M, int Mpad, int G1) {
    __shared__ __align__(16) __bf16 tile[64][68];
    if ((int)blockIdx.x >= G1) {
        // ---- w1 transpose part: bid -> (bx in [0,8), by in [0,16))
        int bid = blockIdx.x - G1;
        int bx = bid & 7, by = bid >> 3;
        int t  = threadIdx.x;
        int tx = t & 15, ty = t >> 4;
        int n0 = bx * 64, k0 = by * 64;
        for (int i = 0; i < 4; i++) {
            int k = k0 + ty + 16 * i;
            float4 v = *(const float4*)(w1 + (size_t)k * N1 + n0 + tx * 4);
            tile[tx * 4 + 0][ty + 16 * i] = (__bf16)v.x;
            tile[tx * 4 + 1][ty + 16 * i] = (__bf16)v.y;
            tile[tx * 4 + 2][ty + 16 * i] = (__bf16)v.z;
            tile[tx * 4 + 3][ty + 16 * i] = (__bf16)v.w;
        }
        __syncthreads();
        for (int i = 0; i < 4; i++) {
            int n = n0 + ty + 16 * i;
            bf16x4 o;
            o[0] = tile[ty + 16 * i][tx * 4 + 0];
            o[1] = tile[ty + 16 * i][tx * 4 + 1];
            o[2] = tile[ty + 16 * i][tx * 4 + 2];
            o[3] = tile[ty + 16 * i][tx * 4 + 3];
            *(bf16x4*)(W1T + (size_t)n * K1 + k0 + tx * 4) = o;
        }
        return;
    }
    int t = blockIdx.x * 256 + threadIdx.x;          // one thread = 8 elems
    // side-task: label columns, interleaved labcol[m*2+br]
    if (t < Mpad * 2) {
        int m = t >> 1, br = t & 1;
        if (m >= M) labcol[m * 2 + br] = -1;
        else {
            int b = m / N, n = m - b * N;
            int tok = br ? seq[b * L + bi[n]] : seq[b * L + fi[n]];
            labcol[m * 2 + br] = br * V + tok;
        }
    }
    int total = Mpad * (K1 / 8);
    if (t >= total) return;
    int m  = t >> 7;              // / (1024/8)
    int c8 = (t & 127) * 8;
    bf16x8 out;
    if (m < M) {
        int b = m / N;
        int n = m - b * N;
        const float* src;
        if (c8 < D) src = fwd + ((size_t)(b * L + fi[n])) * D + c8;
        else        src = bwd + ((size_t)(b * L + bi[n])) * D + (c8 - D);
        float4 v0 = *(const float4*)(src);
        float4 v1 = *(const float4*)(src + 4);
        out[0] = (__bf16)v0.x; out[1] = (__bf16)v0.y;
        out[2] = (__bf16)v0.z; out[3] = (__bf16)v0.w;
        out[4] = (__bf16)v1.x; out[5] = (__bf16)v1.y;
        out[6] = (__bf16)v1.z; out[7] = (__bf16)v1.w;
    } else {
        for (int j = 0; j < 8; j++) out[j] = (__bf16)0.0f;
    }
    *(bf16x8*)(A1 + (size_t)m * K1 + c8) = out;
}

// ---------------------------------------------------------------------------
// GEMM1: H = leaky_relu(A1 @ W1 + b1), emitted in Apack fragment-major
// layout.  128x128 tile, 4 waves (2x2), 16x16x32 MFMA, BK=32.  Epilogue
// round-trips C through LDS so the Apack stores are fully coalesced.
// ---------------------------------------------------------------------------
__global__ __launch_bounds__(256) void gemm1_kernel(
        const __bf16* __restrict__ A, const __bf16* __restrict__ Bt,
        const float* __restrict__ bias, __bf16* __restrict__ Apack, int K) {
    __shared__ __align__(16) __bf16 At[128][40];
    __shared__ __align__(16) __bf16 Bl[128][40];
    __shared__ __align__(16) __bf16 Cld[128][136];
    const int t = threadIdx.x;
    const int by = blockIdx.y, bx = blockIdx.x;
    const int m0 = by * 128, n0 = bx * 128;
    const int srow = t >> 2, schunk = (t & 3) * 8;
    const int wave = t >> 6, lane = t & 63;
    const int wrow = (wave >> 1) * 64, wcol = (wave & 1) * 64;
    const int q = lane >> 4, ln = lane & 15;

    f32x4 acc[4][4] = {};
    for (int k0 = 0; k0 < K; k0 += 32) {
        __syncthreads();
        *(bf16x8*)&At[srow][schunk]      = *(const bf16x8*)(A  + (size_t)(m0 + srow)      * K + k0 + schunk);
        *(bf16x8*)&At[srow + 64][schunk] = *(const bf16x8*)(A  + (size_t)(m0 + srow + 64) * K + k0 + schunk);
        *(bf16x8*)&Bl[srow][schunk]      = *(const bf16x8*)(Bt + (size_t)(n0 + srow)      * K + k0 + schunk);
        *(bf16x8*)&Bl[srow + 64][schunk] = *(const bf16x8*)(Bt + (size_t)(n0 + srow + 64) * K + k0 + schunk);
        __syncthreads();
        bf16x8 af[4], bfr[4];
        for (int i = 0; i < 4; i++) af[i]  = *(const bf16x8*)&At[wrow + i * 16 + ln][q * 8];
        for (int i = 0; i < 4; i++) bfr[i] = *(const bf16x8*)&Bl[wcol + i * 16 + ln][q * 8];
        for (int mi = 0; mi < 4; mi++)
            for (int ni = 0; ni < 4; ni++)
                acc[mi][ni] = MFMA16(af[mi], bfr[ni], acc[mi][ni]);
    }
    // bias + leaky -> LDS C tile
    for (int ni = 0; ni < 4; ni++) {
        int gcol = n0 + wcol + ni * 16 + ln;
        float bv = bias[gcol];
        for (int mi = 0; mi < 4; mi++)
            for (int r = 0; r < 4; r++) {
                float v = acc[mi][ni][r] + bv;
                v = v > 0.0f ? v : 0.01f * v;
                Cld[wrow + mi * 16 + q * 4 + r][wcol + ni * 16 + ln] = (__bf16)v;
            }
    }
    __syncthreads();
    // pack out: 32 chunks (pl 0..1, ksl 0..3, mi 0..3), wave w -> c = w+4i
    for (int i = 0; i < 8; i++) {
        int c   = wave + 4 * i;
        int pl  = c >> 4, ksl = (c >> 2) & 3, mi = c & 3;
        int row = pl * 64 + mi * 16 + (lane & 15);
        int col = ksl * 32 + (lane >> 4) * 8;
        bf16x8 v = *(const bf16x8*)&Cld[row][col];
        size_t base = apack_chunk(2 * by + pl, 4 * bx + ksl, mi);
        *(bf16x8*)(Apack + base + lane * 8) = v;
    }
}

// ---------------------------------------------------------------------------
// GEMM2 (persistent 128-col strip, 1024 threads = 16 waves, 1 block/CU,
// 4 waves/SIMD).  Wave w owns col-half h = w&1 (64 cols) and panel slot
// w>>1 (stride 8) -- the per-wave schedule is R4-VERBATIM (64 AGPR + ~64
// VGPR, spill-free; do not reorder the epilogue: lc -> merged exp/label ->
// reduce).  W2 strip (128 cols x 512 K) staged once fp32->bf16 into
// fragment-major LDS "Bpack" halves (128 KB; conflict-free b128;
// non-temporal loads protect Apack's L2 residency).  A frags from L2 with
// one-k-step prefetch; sibling col-half waves re-hit A in L1.
// Partial row = 2*strip + h (1000 rows).
// ---------------------------------------------------------------------------
__global__ __launch_bounds__(1024, 4) void gemm2_kernel(
        const __bf16* __restrict__ Apack, const float* __restrict__ w2,
        const float* __restrict__ b2, const int* __restrict__ labcol,
        float* __restrict__ partial, float* __restrict__ lab,
        int M, int Mpad) {
    __shared__ __align__(16) __bf16 Bp[SW * 512];   // 128 KB, fragment-major
    const int t = threadIdx.x;
    const int strip = blockIdx.x;
    const int c0 = strip * SW;

    // ---- stage W2 strip fp32 [512][64000] -> Bpack bf16, two 64-col halves
    // each laid out exactly like R8's 64-col fragment-major Bpack.
    {
        const int col = t & 127;                    // 0..127
        const int hh = col >> 6, colh = col & 63;
        const int ni = colh >> 4, lncol = colh & 15;
        const int kb0 = (t >> 7) * 8;               // 0,8,...,56
        for (int r = 0; r < 8; r++) {
            int kb = kb0 + r * 64;                  // all multiples of 8 in [0,512)
            int ks = kb >> 5, qk = (kb >> 3) & 3;
            float v[8];
#pragma unroll
            for (int j = 0; j < 8; j++)
                v[j] = __builtin_nontemporal_load(w2 + (size_t)(kb + j) * N2 + c0 + col);
            bf16x8 o;
#pragma unroll
            for (int j = 0; j < 8; j++) o[j] = (__bf16)v[j];
            *(bf16x8*)&Bp[(size_t)(hh * 4096 + (ks * 4 + ni) * 64 + qk * 16 + lncol) * 8] = o;
        }
    }
    __syncthreads();

    const int wave = t >> 6, lane = t & 63;
    const int h = wave & 1, pslot = wave >> 1;
    const __bf16* __restrict__ BpW = Bp + ((size_t)h << 15);  // h*64*512
    const int c0w = c0 + h * 64;
    const int branch = (c0w >= V) ? 1 : 0;          // halves never straddle V
    const int q = lane >> 4, ln = lane & 15;

    float bvn[4];
#pragma unroll
    for (int ni = 0; ni < 4; ni++) bvn[ni] = b2[c0w + ni * 16 + ln];

    const int prow = strip * 2 + h;                 // partial row index
    const int npanels = Mpad >> 6;
    for (int p = pslot; p < npanels; p += 8) {
        if (p * 64 >= M) break;   // all-padding panel: nothing downstream reads it

        const __bf16* base = Apack + apack_chunk(p, 0, 0) + lane * 8;

        f32x4 acc[4][4] = {};
        bf16x8 afc[4], afn[4];
#pragma unroll
        for (int mi = 0; mi < 4; mi++)
            afc[mi] = *(const bf16x8*)(base + mi * 512);
#pragma unroll 1
        for (int ks = 0; ks < 16; ks++) {
            if (ks < 15) {
#pragma unroll
                for (int mi = 0; mi < 4; mi++)
                    afn[mi] = *(const bf16x8*)(base + (size_t)(ks + 1) * 2048 + mi * 512);
            }
            bf16x8 bf[4];
#pragma unroll
            for (int ni = 0; ni < 4; ni++)
                bf[ni] = *(const bf16x8*)&BpW[(size_t)(ks * 4 + ni) * 512 + lane * 8];
#pragma unroll
            for (int mi = 0; mi < 4; mi++)
#pragma unroll
                for (int ni = 0; ni < 4; ni++)
                    acc[mi][ni] = MFMA16(afc[mi], bf[ni], acc[mi][ni]);
#pragma unroll
            for (int mi = 0; mi < 4; mi++) afc[mi] = afn[mi];
        }

        // ---- epilogue for this panel (R4 order)
        int lc[4][4];
#pragma unroll
        for (int mi = 0; mi < 4; mi++)
#pragma unroll
            for (int r = 0; r < 4; r++)
                lc[mi][r] = labcol[(p * 64 + mi * 16 + q * 4 + r) * 2 + branch];

        float rowsum[4][4];
#pragma unroll
        for (int mi = 0; mi < 4; mi++)
#pragma unroll
            for (int r = 0; r < 4; r++) rowsum[mi][r] = 0.0f;

#pragma unroll
        for (int ni = 0; ni < 4; ni++) {
            const int gcol = c0w + ni * 16 + ln;
            const float bv = bvn[ni];
#pragma unroll
            for (int mi = 0; mi < 4; mi++)
#pragma unroll
                for (int r = 0; r < 4; r++) {
                    float v = acc[mi][ni][r] + bv;
                    rowsum[mi][r] += __expf(v);
                    if (gcol == lc[mi][r]) {
                        int gm = p * 64 + mi * 16 + q * 4 + r;
                        lab[gm * 2 + branch] = v;
                    }
                }
        }
        // reduce over the 16 column-lanes (lane bits 0..3)
#pragma unroll
        for (int mi = 0; mi < 4; mi++)
#pragma unroll
            for (int r = 0; r < 4; r++) {
                float s = rowsum[mi][r];
                s += __shfl_xor(s, 1);
                s += __shfl_xor(s, 2);
                s += __shfl_xor(s, 4);
                s += __shfl_xor(s, 8);
                rowsum[mi][r] = s;
            }
        // per-lane row gather: lane l wants row l = mi*16 + q*4 + r; value
        // lives in lanes with q-src = (l>>2)&3 at register rowsum[l>>4][l&3].
        float mine = 0.0f;
        const int srcl = ((lane >> 2) & 3) * 16;
#pragma unroll
        for (int mi2 = 0; mi2 < 4; mi2++)
#pragma unroll
            for (int r2 = 0; r2 < 4; r2++) {
                float tv = __shfl(rowsum[mi2][r2], srcl);
                if ((lane >> 4) == mi2 && (lane & 3) == r2) mine = tv;
            }
        partial[(size_t)prow * Mpad + p * 64 + lane] = mine;
    }
}

// ---------------------------------------------------------------------------
// Fused final: block per (64-row panel, branch). 4 waves stride the branch's
// 500 partial rows, coalesced 256 B reads, LDS combine, then wave 0 computes
// nll = log(sumexp) - lab, weights, reduces, atomicAdd into out.
// ---------------------------------------------------------------------------
__global__ __launch_bounds__(256) void final_kernel(
        const float* __restrict__ partial, const float* __restrict__ lab,
        float* __restrict__ out, int M, int Mpad) {
    __shared__ float red[4][64];
    const int br = blockIdx.x & 1;
    const int m0 = (blockIdx.x >> 1) * 64;
    const int wave = threadIdx.x >> 6, lane = threadIdx.x & 63;
    float s = 0.0f;
    for (int i = wave; i < NPART / 2; i += 4)
        s += partial[(size_t)(br * (NPART / 2) + i) * Mpad + m0 + lane];
    red[wave][lane] = s;
    __syncthreads();
    if (wave == 0) {
        float tot = red[0][lane] + red[1][lane] + red[2][lane] + red[3][lane];
        int m = m0 + lane;
        float acc = 0.0f;
        if (m < M)
            acc = (br ? 0.25f : 1.0f) * (logf(tot) - lab[m * 2 + br]);
        acc += __shfl_xor(acc, 32);
        acc += __shfl_xor(acc, 16);
        acc += __shfl_xor(acc, 8);
        acc += __shfl_xor(acc, 4);
        acc += __shfl_xor(acc, 2);
        acc += __shfl_xor(acc, 1);
        if (lane == 0) atomicAdd(out, acc / (float)(2 * M));
    }
}

// ---------------------------------------------------------------------------
extern "C" void kernel_launch(void* const* d_in, const int* in_sizes, int n_in,
                              void* d_out, int out_size, void* d_ws, size_t ws_size,
                              hipStream_t stream) {
    const float* fwd = (const float*)d_in[0];
    const float* bwd = (const float*)d_in[1];
    const int*   seq = (const int*)d_in[2];
    const int*   fi  = (const int*)d_in[3];
    const int*   bi  = (const int*)d_in[4];
    const float* w1  = (const float*)d_in[5];
    const float* b1  = (const float*)d_in[6];
    const float* w2  = (const float*)d_in[7];
    const float* b2  = (const float*)d_in[8];
    float* out = (float*)d_out;

    const int N    = in_sizes[3];              // 1303
    const int M    = Bsz * N;                  // 2606
    const int Mpad = ((M + 127) / 128) * 128;  // 2688 (gemm1 needs 128-row multiples)

    // workspace layout (16B-aligned slices)
    char* ws = (char*)d_ws;
    __bf16* A1    = (__bf16*)(ws);                                   // Mpad*1024
    __bf16* W1T   = (__bf16*)(ws + (size_t)Mpad * K1 * 2);           // 512*1024
    __bf16* Apack = (__bf16*)((char*)W1T + (size_t)N1 * K1 * 2);     // Mpad*512
    float*  partial = (float*)((char*)Apack + (size_t)Mpad * N1 * 2);// NPART*Mpad
    float*  lab     = (float*)((char*)partial + (size_t)NPART * Mpad * 4); // Mpad*2
    int*    labcol  = (int*)((char*)lab + (size_t)Mpad * 2 * 4);     // Mpad*2

    // 1. fused prep: gather+cast (+labcol interleaved) and w1 transpose
    {
        int G1 = Mpad * (K1 / 8) / 256;        // gather blocks (Mpad*128 % 256 == 0)
        prep_kernel<<<G1 + 128, 256, 0, stream>>>(
            fwd, bwd, fi, bi, seq, w1, A1, W1T, labcol, N, M, Mpad, G1);
    }
    // 2. zero the output accumulator
    hipMemsetAsync(out, 0, sizeof(float), stream);
    // 3. GEMM1 -> Apack (fragment-major H)
    gemm1_kernel<<<dim3(N1 / 128, Mpad / 128), 256, 0, stream>>>(A1, W1T, b1, Apack, K1);
    // 4. GEMM2 persistent 128-col strips (16 waves) -> partial rowsums + labels
    gemm2_kernel<<<NSTRIP, 1024, 0, stream>>>(Apack, w2, b2, labcol, partial, lab, M, Mpad);
    // 5. fused final: strip-reduce + NLL + weighted mean -> out
    //    (only panels that contain real rows)
    final_kernel<<<((M + 63) / 64) * 2, 256, 0, stream>>>(partial, lab, out, M, Mpad);
}

// Round 6
// 411.857 us; speedup vs baseline: 1.0392x; 1.0392x over previous
//
#include <hip/hip_runtime.h>

// ---------------------------------------------------------------------------
// BeliefStateWrapper: gather(fi,bi) -> Linear(1024->512)+LeakyReLU ->
// Linear(512->64000) -> per-branch log_softmax NLL -> weighted mean (scalar).
//
// R14: exact R8 revert + ping-pong K-loop in gemm2.
// History: R9 (desync/setprio) null; R10 (panel-skip/exp2/unroll-cap) -9us
// regression; R11 (W=128, 2 waves/SIMD) -18us; R12 (W=128, 16 waves) -7us
// with A-L2 halved -> A-traffic volume is NOT the binding term (R8's two
// blocks/CU already dedupe A via L1). Binding term: per-wave latency chain.
// R8's `afc=afn` copies force vmcnt(0)+16 v_mov at the END of each ks,
// before the next ks can issue -- a drain-to-0 per step. R14 unrolls ks by
// 2 with ping-pong A buffers (afA/afB): no copies, each load's wait lands
// just before its consuming MFMAs one full iteration after issue. Same
// live-register footprint (VGPR must stay 64 -- the 128-unified-reg
// bracket at 4 waves/SIMD is the occupancy cliff).
// Everything else is R8-VERBATIM (Mpad 2816, 64-col strips, R4 epilogue
// order lc -> merged exp/label -> reduce; do not reorder).
// ---------------------------------------------------------------------------

typedef __bf16 bf16x8 __attribute__((ext_vector_type(8)));
typedef __bf16 bf16x4 __attribute__((ext_vector_type(4)));
typedef float f32x4  __attribute__((ext_vector_type(4)));

#define MFMA16(a, b, c) __builtin_amdgcn_mfma_f32_16x16x32_bf16(a, b, c, 0, 0, 0)

static constexpr int Bsz   = 2;
static constexpr int L     = 512;
static constexpr int D     = 512;
static constexpr int V     = 32000;
static constexpr int K1    = 2 * D;      // 1024
static constexpr int N1    = D;          // 512
static constexpr int K2    = D;          // 512
static constexpr int N2    = 2 * V;      // 64000
static constexpr int NSTRIP = N2 / 64;   // 1000 strips (500 per branch)

// Apack chunk base (bf16 elems) for (panel, ks, mi); chunk = 64 lanes x 8
// bf16 = 512 elems = 1 KB. Lane l holds A[panel*64+mi*16+(l&15)]
// [ks*32+(l>>4)*8 .. +7].
__device__ __host__ inline size_t apack_chunk(int panel, int ks, int mi) {
    return (((size_t)panel * 16 + ks) * 4 + mi) * 512;
}

// ---------------------------------------------------------------------------
// prep kernel: blocks [0, G1) do gather+cast (+labcol side-task, interleaved
// labcol[m*2+br] layout); blocks [G1, G1+128) transpose+cast w1 -> W1T.
// ---------------------------------------------------------------------------
__global__ void prep_kernel(const float* __restrict__ fwd,
                            const float* __restrict__ bwd,
                            const int* __restrict__ fi,
                            const int* __restrict__ bi,
                            const int* __restrict__ seq,
                            const float* __restrict__ w1,
                            __bf16* __restrict__ A1,
                            __bf16* __restrict__ W1T,
                            int* __restrict__ labcol,
                            int N, int M, int Mpad, int G1) {
    __shared__ __align__(16) __bf16 tile[64][68];
    if ((int)blockIdx.x >= G1) {
        // ---- w1 transpose part: bid -> (bx in [0,8), by in [0,16))
        int bid = blockIdx.x - G1;
        int bx = bid & 7, by = bid >> 3;
        int t  = threadIdx.x;
        int tx = t & 15, ty = t >> 4;
        int n0 = bx * 64, k0 = by * 64;
        for (int i = 0; i < 4; i++) {
            int k = k0 + ty + 16 * i;
            float4 v = *(const float4*)(w1 + (size_t)k * N1 + n0 + tx * 4);
            tile[tx * 4 + 0][ty + 16 * i] = (__bf16)v.x;
            tile[tx * 4 + 1][ty + 16 * i] = (__bf16)v.y;
            tile[tx * 4 + 2][ty + 16 * i] = (__bf16)v.z;
            tile[tx * 4 + 3][ty + 16 * i] = (__bf16)v.w;
        }
        __syncthreads();
        for (int i = 0; i < 4; i++) {
            int n = n0 + ty + 16 * i;
            bf16x4 o;
            o[0] = tile[ty + 16 * i][tx * 4 + 0];
            o[1] = tile[ty + 16 * i][tx * 4 + 1];
            o[2] = tile[ty + 16 * i][tx * 4 + 2];
            o[3] = tile[ty + 16 * i][tx * 4 + 3];
            *(bf16x4*)(W1T + (size_t)n * K1 + k0 + tx * 4) = o;
        }
        return;
    }
    int t = blockIdx.x * 256 + threadIdx.x;          // one thread = 8 elems
    // side-task: label columns, interleaved labcol[m*2+br]
    if (t < Mpad * 2) {
        int m = t >> 1, br = t & 1;
        if (m >= M) labcol[m * 2 + br] = -1;
        else {
            int b = m / N, n = m - b * N;
            int tok = br ? seq[b * L + bi[n]] : seq[b * L + fi[n]];
            labcol[m * 2 + br] = br * V + tok;
        }
    }
    int total = Mpad * (K1 / 8);
    if (t >= total) return;
    int m  = t >> 7;              // / (1024/8)
    int c8 = (t & 127) * 8;
    bf16x8 out;
    if (m < M) {
        int b = m / N;
        int n = m - b * N;
        const float* src;
        if (c8 < D) src = fwd + ((size_t)(b * L + fi[n])) * D + c8;
        else        src = bwd + ((size_t)(b * L + bi[n])) * D + (c8 - D);
        float4 v0 = *(const float4*)(src);
        float4 v1 = *(const float4*)(src + 4);
        out[0] = (__bf16)v0.x; out[1] = (__bf16)v0.y;
        out[2] = (__bf16)v0.z; out[3] = (__bf16)v0.w;
        out[4] = (__bf16)v1.x; out[5] = (__bf16)v1.y;
        out[6] = (__bf16)v1.z; out[7] = (__bf16)v1.w;
    } else {
        for (int j = 0; j < 8; j++) out[j] = (__bf16)0.0f;
    }
    *(bf16x8*)(A1 + (size_t)m * K1 + c8) = out;
}

// ---------------------------------------------------------------------------
// GEMM1: H = leaky_relu(A1 @ W1 + b1), emitted in Apack fragment-major
// layout.  128x128 tile, 4 waves (2x2), 16x16x32 MFMA, BK=32.  Epilogue
// round-trips C through LDS so the Apack stores are fully coalesced.
// ---------------------------------------------------------------------------
__global__ __launch_bounds__(256) void gemm1_kernel(
        const __bf16* __restrict__ A, const __bf16* __restrict__ Bt,
        const float* __restrict__ bias, __bf16* __restrict__ Apack, int K) {
    __shared__ __align__(16) __bf16 At[128][40];
    __shared__ __align__(16) __bf16 Bl[128][40];
    __shared__ __align__(16) __bf16 Cld[128][136];
    const int t = threadIdx.x;
    const int by = blockIdx.y, bx = blockIdx.x;
    const int m0 = by * 128, n0 = bx * 128;
    const int srow = t >> 2, schunk = (t & 3) * 8;
    const int wave = t >> 6, lane = t & 63;
    const int wrow = (wave >> 1) * 64, wcol = (wave & 1) * 64;
    const int q = lane >> 4, ln = lane & 15;

    f32x4 acc[4][4] = {};
    for (int k0 = 0; k0 < K; k0 += 32) {
        __syncthreads();
        *(bf16x8*)&At[srow][schunk]      = *(const bf16x8*)(A  + (size_t)(m0 + srow)      * K + k0 + schunk);
        *(bf16x8*)&At[srow + 64][schunk] = *(const bf16x8*)(A  + (size_t)(m0 + srow + 64) * K + k0 + schunk);
        *(bf16x8*)&Bl[srow][schunk]      = *(const bf16x8*)(Bt + (size_t)(n0 + srow)      * K + k0 + schunk);
        *(bf16x8*)&Bl[srow + 64][schunk] = *(const bf16x8*)(Bt + (size_t)(n0 + srow + 64) * K + k0 + schunk);
        __syncthreads();
        bf16x8 af[4], bfr[4];
        for (int i = 0; i < 4; i++) af[i]  = *(const bf16x8*)&At[wrow + i * 16 + ln][q * 8];
        for (int i = 0; i < 4; i++) bfr[i] = *(const bf16x8*)&Bl[wcol + i * 16 + ln][q * 8];
        for (int mi = 0; mi < 4; mi++)
            for (int ni = 0; ni < 4; ni++)
                acc[mi][ni] = MFMA16(af[mi], bfr[ni], acc[mi][ni]);
    }
    // bias + leaky -> LDS C tile
    for (int ni = 0; ni < 4; ni++) {
        int gcol = n0 + wcol + ni * 16 + ln;
        float bv = bias[gcol];
        for (int mi = 0; mi < 4; mi++)
            for (int r = 0; r < 4; r++) {
                float v = acc[mi][ni][r] + bv;
                v = v > 0.0f ? v : 0.01f * v;
                Cld[wrow + mi * 16 + q * 4 + r][wcol + ni * 16 + ln] = (__bf16)v;
            }
    }
    __syncthreads();
    // pack out: 32 chunks (pl 0..1, ksl 0..3, mi 0..3), wave w -> c = w+4i
    for (int i = 0; i < 8; i++) {
        int c   = wave + 4 * i;
        int pl  = c >> 4, ksl = (c >> 2) & 3, mi = c & 3;
        int row = pl * 64 + mi * 16 + (lane & 15);
        int col = ksl * 32 + (lane >> 4) * 8;
        bf16x8 v = *(const bf16x8*)&Cld[row][col];
        size_t base = apack_chunk(2 * by + pl, 4 * bx + ksl, mi);
        *(bf16x8*)(Apack + base + lane * 8) = v;
    }
}

// ---------------------------------------------------------------------------
// GEMM2 (persistent 64-col strip, 512 threads = 8 waves, 2 blocks/CU) --
// R4 schedule with R14 ping-pong K-loop (spill-free at the 64-arch-VGPR
// cap; do not reorder the epilogue: lc loads -> merged label/exp loop ->
// reduce).  W2 strip staged once fp32->bf16 into fragment-major LDS
// "Bpack" (conflict-free b128; non-temporal loads protect Apack's L2
// residency).  A frags from L2; ks unrolled x2 with alternating afA/afB
// buffers so there is no afc=afn copy and no per-ks vmcnt(0) drain --
// each load's wait lands just before its consuming MFMAs, one full
// iteration after issue.  Live A-regs: 32 VGPR (same as R8).
// ---------------------------------------------------------------------------
__global__ __launch_bounds__(512, 4) void gemm2_kernel(
        const __bf16* __restrict__ Apack, const float* __restrict__ w2,
        const float* __restrict__ b2, const int* __restrict__ labcol,
        float* __restrict__ partial, float* __restrict__ lab, int Mpad) {
    __shared__ __align__(16) __bf16 Bp[64 * 512];   // 64 KB, fragment-major
    const int t = threadIdx.x;
    const int strip = blockIdx.x;
    const int c0 = strip * 64;
    const int branch = (c0 >= V) ? 1 : 0;

    // ---- stage W2 strip fp32 [512][64000] -> Bpack bf16
    {
        const int col = t & 63;
        const int ni = col >> 4, lncol = col & 15;
        const int kb0 = (t >> 6) * 8;
        for (int r = 0; r < 8; r++) {
            int kb = kb0 + r * 64;
            int ks = kb >> 5, qk = (kb >> 3) & 3;
            float v[8];
#pragma unroll
            for (int j = 0; j < 8; j++)
                v[j] = __builtin_nontemporal_load(w2 + (size_t)(kb + j) * N2 + c0 + col);
            bf16x8 o;
#pragma unroll
            for (int j = 0; j < 8; j++) o[j] = (__bf16)v[j];
            *(bf16x8*)&Bp[(size_t)(((ks * 4 + ni) * 64 + qk * 16 + lncol)) * 8] = o;
        }
    }
    __syncthreads();

    const int wave = t >> 6, lane = t & 63;
    const int q = lane >> 4, ln = lane & 15;

    float bvn[4];
#pragma unroll
    for (int ni = 0; ni < 4; ni++) bvn[ni] = b2[c0 + ni * 16 + ln];

    const int npanels = Mpad >> 6;
    for (int p = wave; p < npanels; p += 8) {
        const __bf16* base = Apack + apack_chunk(p, 0, 0) + lane * 8;

        f32x4 acc[4][4] = {};
        bf16x8 afA[4], afB[4];
#pragma unroll
        for (int mi = 0; mi < 4; mi++)
            afA[mi] = *(const bf16x8*)(base + mi * 512);
#pragma unroll 1
        for (int ks = 0; ks < 16; ks += 2) {
            // even half: prefetch ks+1 into afB, compute with afA
            {
#pragma unroll
                for (int mi = 0; mi < 4; mi++)
                    afB[mi] = *(const bf16x8*)(base + (size_t)(ks + 1) * 2048 + mi * 512);
                bf16x8 bf[4];
#pragma unroll
                for (int ni = 0; ni < 4; ni++)
                    bf[ni] = *(const bf16x8*)&Bp[(size_t)(ks * 4 + ni) * 512 + lane * 8];
#pragma unroll
                for (int mi = 0; mi < 4; mi++)
#pragma unroll
                    for (int ni = 0; ni < 4; ni++)
                        acc[mi][ni] = MFMA16(afA[mi], bf[ni], acc[mi][ni]);
            }
            // odd half: prefetch ks+2 into afA, compute with afB
            {
                if (ks + 2 < 16) {
#pragma unroll
                    for (int mi = 0; mi < 4; mi++)
                        afA[mi] = *(const bf16x8*)(base + (size_t)(ks + 2) * 2048 + mi * 512);
                }
                bf16x8 bf[4];
#pragma unroll
                for (int ni = 0; ni < 4; ni++)
                    bf[ni] = *(const bf16x8*)&Bp[(size_t)((ks + 1) * 4 + ni) * 512 + lane * 8];
#pragma unroll
                for (int mi = 0; mi < 4; mi++)
#pragma unroll
                    for (int ni = 0; ni < 4; ni++)
                        acc[mi][ni] = MFMA16(afB[mi], bf[ni], acc[mi][ni]);
            }
        }

        // ---- epilogue for this panel (R4 order)
        int lc[4][4];
#pragma unroll
        for (int mi = 0; mi < 4; mi++)
#pragma unroll
            for (int r = 0; r < 4; r++)
                lc[mi][r] = labcol[(p * 64 + mi * 16 + q * 4 + r) * 2 + branch];

        float rowsum[4][4];
#pragma unroll
        for (int mi = 0; mi < 4; mi++)
#pragma unroll
            for (int r = 0; r < 4; r++) rowsum[mi][r] = 0.0f;

#pragma unroll
        for (int ni = 0; ni < 4; ni++) {
            const int gcol = c0 + ni * 16 + ln;
            const float bv = bvn[ni];
#pragma unroll
            for (int mi = 0; mi < 4; mi++)
#pragma unroll
                for (int r = 0; r < 4; r++) {
                    float v = acc[mi][ni][r] + bv;
                    rowsum[mi][r] += __expf(v);
                    if (gcol == lc[mi][r]) {
                        int gm = p * 64 + mi * 16 + q * 4 + r;
                        lab[gm * 2 + branch] = v;
                    }
                }
        }
        // reduce over the 16 column-lanes (lane bits 0..3)
#pragma unroll
        for (int mi = 0; mi < 4; mi++)
#pragma unroll
            for (int r = 0; r < 4; r++) {
                float s = rowsum[mi][r];
                s += __shfl_xor(s, 1);
                s += __shfl_xor(s, 2);
                s += __shfl_xor(s, 4);
                s += __shfl_xor(s, 8);
                rowsum[mi][r] = s;
            }
        // per-lane row gather: lane l wants row l = mi*16 + q*4 + r; value
        // lives in lanes with q-src = (l>>2)&3 at register rowsum[l>>4][l&3].
        float mine = 0.0f;
        const int srcl = ((lane >> 2) & 3) * 16;
#pragma unroll
        for (int mi2 = 0; mi2 < 4; mi2++)
#pragma unroll
            for (int r2 = 0; r2 < 4; r2++) {
                float tv = __shfl(rowsum[mi2][r2], srcl);
                if ((lane >> 4) == mi2 && (lane & 3) == r2) mine = tv;
            }
        partial[(size_t)strip * Mpad + p * 64 + lane] = mine;
    }
}

// ---------------------------------------------------------------------------
// Fused final: block per (64-row panel, branch). 4 waves split the branch's
// 500 strips (125 each), coalesced 256 B reads, LDS combine, then wave 0
// computes nll = log(sumexp) - lab, weights, reduces, atomicAdd into out.
// ---------------------------------------------------------------------------
__global__ __launch_bounds__(256) void final_kernel(
        const float* __restrict__ partial, const float* __restrict__ lab,
        float* __restrict__ out, int M, int Mpad) {
    __shared__ float red[4][64];
    const int br = blockIdx.x & 1;
    const int m0 = (blockIdx.x >> 1) * 64;
    const int wave = threadIdx.x >> 6, lane = threadIdx.x & 63;
    const int s0 = br * (NSTRIP / 2) + wave * (NSTRIP / 8);
    float s = 0.0f;
#pragma unroll 5
    for (int i = 0; i < NSTRIP / 8; i++)
        s += partial[(size_t)(s0 + i) * Mpad + m0 + lane];
    red[wave][lane] = s;
    __syncthreads();
    if (wave == 0) {
        float tot = red[0][lane] + red[1][lane] + red[2][lane] + red[3][lane];
        int m = m0 + lane;
        float acc = 0.0f;
        if (m < M)
            acc = (br ? 0.25f : 1.0f) * (logf(tot) - lab[m * 2 + br]);
        acc += __shfl_xor(acc, 32);
        acc += __shfl_xor(acc, 16);
        acc += __shfl_xor(acc, 8);
        acc += __shfl_xor(acc, 4);
        acc += __shfl_xor(acc, 2);
        acc += __shfl_xor(acc, 1);
        if (lane == 0) atomicAdd(out, acc / (float)(2 * M));
    }
}

// ---------------------------------------------------------------------------
extern "C" void kernel_launch(void* const* d_in, const int* in_sizes, int n_in,
                              void* d_out, int out_size, void* d_ws, size_t ws_size,
                              hipStream_t stream) {
    const float* fwd = (const float*)d_in[0];
    const float* bwd = (const float*)d_in[1];
    const int*   seq = (const int*)d_in[2];
    const int*   fi  = (const int*)d_in[3];
    const int*   bi  = (const int*)d_in[4];
    const float* w1  = (const float*)d_in[5];
    const float* b1  = (const float*)d_in[6];
    const float* w2  = (const float*)d_in[7];
    const float* b2  = (const float*)d_in[8];
    float* out = (float*)d_out;

    const int N    = in_sizes[3];              // 1303
    const int M    = Bsz * N;                  // 2606
    const int Mpad = ((M + 255) / 256) * 256;  // 2816

    // workspace layout (16B-aligned slices)
    char* ws = (char*)d_ws;
    __bf16* A1    = (__bf16*)(ws);                                   // Mpad*1024
    __bf16* W1T   = (__bf16*)(ws + (size_t)Mpad * K1 * 2);           // 512*1024
    __bf16* Apack = (__bf16*)((char*)W1T + (size_t)N1 * K1 * 2);     // Mpad*512
    float*  partial = (float*)((char*)Apack + (size_t)Mpad * N1 * 2);// NSTRIP*Mpad
    float*  lab     = (float*)((char*)partial + (size_t)NSTRIP * Mpad * 4); // Mpad*2
    int*    labcol  = (int*)((char*)lab + (size_t)Mpad * 2 * 4);     // Mpad*2

    // 1. fused prep: gather+cast (+labcol interleaved) and w1 transpose
    {
        int G1 = Mpad * (K1 / 8) / 256;        // gather blocks
        prep_kernel<<<G1 + 128, 256, 0, stream>>>(
            fwd, bwd, fi, bi, seq, w1, A1, W1T, labcol, N, M, Mpad, G1);
    }
    // 2. zero the output accumulator
    hipMemsetAsync(out, 0, sizeof(float), stream);
    // 3. GEMM1 -> Apack (fragment-major H)
    gemm1_kernel<<<dim3(N1 / 128, Mpad / 128), 256, 0, stream>>>(A1, W1T, b1, Apack, K1);
    // 4. GEMM2 persistent strips -> per-strip partial rowsums + labels
    gemm2_kernel<<<NSTRIP, 512, 0, stream>>>(Apack, w2, b2, labcol, partial, lab, Mpad);
    // 5. fused final: strip-reduce + NLL + weighted mean -> out
    final_kernel<<<(Mpad / 64) * 2, 256, 0, stream>>>(partial, lab, out, M, Mpad);
}

// Round 7
// 394.105 us; speedup vs baseline: 1.0860x; 1.0450x over previous
//
#include <hip/hip_runtime.h>

// ---------------------------------------------------------------------------
// BeliefStateWrapper: gather(fi,bi) -> Linear(1024->512)+LeakyReLU ->
// Linear(512->64000) -> per-branch log_softmax NLL -> weighted mean (scalar).
//
// R15: consolidation. gemm2 reverted to R8-VERBATIM (200.8 us anchor).
// Closed-out gemm2 record: R9 desync null, R10 trims -9, R11 W128@2w -18,
// R12 W128@16w -7, R14 ping-pong -7 (but proved the afc=afn copies were
// off-critical-path: VALUBusy -6pts, dur flat). Cycle model: per CU round
// = serial sum TCP(1024)+LDS(768)+MFMA(1240) ~= 2790 measured; overlap
// levers all blocked by the 128-unified-reg cliff (acc=64 AGPR floor) or
// the LDS box (2x64KB Bp leaves no LDS-A for 8-phase choreography).
// R8 schedule = this algorithm's floor. R15 targets the ~200us residual:
//   (a) out zeroed by prep (drops the hipMemsetAsync dispatch);
//   (b) gemm1 register-dbuf staging (next k-chunk loads overlap MFMA,
//       removing the per-step vmcnt(0) stall; ~4us).
// ---------------------------------------------------------------------------

typedef __bf16 bf16x8 __attribute__((ext_vector_type(8)));
typedef __bf16 bf16x4 __attribute__((ext_vector_type(4)));
typedef float f32x4  __attribute__((ext_vector_type(4)));

#define MFMA16(a, b, c) __builtin_amdgcn_mfma_f32_16x16x32_bf16(a, b, c, 0, 0, 0)

static constexpr int Bsz   = 2;
static constexpr int L     = 512;
static constexpr int D     = 512;
static constexpr int V     = 32000;
static constexpr int K1    = 2 * D;      // 1024
static constexpr int N1    = D;          // 512
static constexpr int K2    = D;          // 512
static constexpr int N2    = 2 * V;      // 64000
static constexpr int NSTRIP = N2 / 64;   // 1000 strips (500 per branch)

// Apack chunk base (bf16 elems) for (panel, ks, mi); chunk = 64 lanes x 8
// bf16 = 512 elems = 1 KB. Lane l holds A[panel*64+mi*16+(l&15)]
// [ks*32+(l>>4)*8 .. +7].
__device__ __host__ inline size_t apack_chunk(int panel, int ks, int mi) {
    return (((size_t)panel * 16 + ks) * 4 + mi) * 512;
}

// ---------------------------------------------------------------------------
// prep kernel: blocks [0, G1) do gather+cast (+labcol side-task, interleaved
// labcol[m*2+br] layout); blocks [G1, G1+128) transpose+cast w1 -> W1T.
// Block 0 thread 0 also zeroes the output accumulator (replaces the
// hipMemsetAsync dispatch).
// ---------------------------------------------------------------------------
__global__ void prep_kernel(const float* __restrict__ fwd,
                            const float* __restrict__ bwd,
                            const int* __restrict__ fi,
                            const int* __restrict__ bi,
                            const int* __restrict__ seq,
                            const float* __restrict__ w1,
                            __bf16* __restrict__ A1,
                            __bf16* __restrict__ W1T,
                            int* __restrict__ labcol,
                            float* __restrict__ out,
                            int N, int M, int Mpad, int G1) {
    __shared__ __align__(16) __bf16 tile[64][68];
    if ((int)blockIdx.x >= G1) {
        // ---- w1 transpose part: bid -> (bx in [0,8), by in [0,16))
        int bid = blockIdx.x - G1;
        int bx = bid & 7, by = bid >> 3;
        int t  = threadIdx.x;
        int tx = t & 15, ty = t >> 4;
        int n0 = bx * 64, k0 = by * 64;
        for (int i = 0; i < 4; i++) {
            int k = k0 + ty + 16 * i;
            float4 v = *(const float4*)(w1 + (size_t)k * N1 + n0 + tx * 4);
            tile[tx * 4 + 0][ty + 16 * i] = (__bf16)v.x;
            tile[tx * 4 + 1][ty + 16 * i] = (__bf16)v.y;
            tile[tx * 4 + 2][ty + 16 * i] = (__bf16)v.z;
            tile[tx * 4 + 3][ty + 16 * i] = (__bf16)v.w;
        }
        __syncthreads();
        for (int i = 0; i < 4; i++) {
            int n = n0 + ty + 16 * i;
            bf16x4 o;
            o[0] = tile[ty + 16 * i][tx * 4 + 0];
            o[1] = tile[ty + 16 * i][tx * 4 + 1];
            o[2] = tile[ty + 16 * i][tx * 4 + 2];
            o[3] = tile[ty + 16 * i][tx * 4 + 3];
            *(bf16x4*)(W1T + (size_t)n * K1 + k0 + tx * 4) = o;
        }
        return;
    }
    int t = blockIdx.x * 256 + threadIdx.x;          // one thread = 8 elems
    if (t == 0) *out = 0.0f;                          // replaces memset launch
    // side-task: label columns, interleaved labcol[m*2+br]
    if (t < Mpad * 2) {
        int m = t >> 1, br = t & 1;
        if (m >= M) labcol[m * 2 + br] = -1;
        else {
            int b = m / N, n = m - b * N;
            int tok = br ? seq[b * L + bi[n]] : seq[b * L + fi[n]];
            labcol[m * 2 + br] = br * V + tok;
        }
    }
    int total = Mpad * (K1 / 8);
    if (t >= total) return;
    int m  = t >> 7;              // / (1024/8)
    int c8 = (t & 127) * 8;
    bf16x8 out8;
    if (m < M) {
        int b = m / N;
        int n = m - b * N;
        const float* src;
        if (c8 < D) src = fwd + ((size_t)(b * L + fi[n])) * D + c8;
        else        src = bwd + ((size_t)(b * L + bi[n])) * D + (c8 - D);
        float4 v0 = *(const float4*)(src);
        float4 v1 = *(const float4*)(src + 4);
        out8[0] = (__bf16)v0.x; out8[1] = (__bf16)v0.y;
        out8[2] = (__bf16)v0.z; out8[3] = (__bf16)v0.w;
        out8[4] = (__bf16)v1.x; out8[5] = (__bf16)v1.y;
        out8[6] = (__bf16)v1.z; out8[7] = (__bf16)v1.w;
    } else {
        for (int j = 0; j < 8; j++) out8[j] = (__bf16)0.0f;
    }
    *(bf16x8*)(A1 + (size_t)m * K1 + c8) = out8;
}

// ---------------------------------------------------------------------------
// GEMM1: H = leaky_relu(A1 @ W1 + b1), emitted in Apack fragment-major
// layout.  128x128 tile, 4 waves (2x2), 16x16x32 MFMA, BK=32.
// R15: register-double-buffered staging -- the next k-chunk's 4 global
// loads are issued right after the staging barrier and consumed (reg->LDS)
// at the top of the NEXT iteration, so their latency hides under the
// current iteration's ds_read+MFMA instead of stalling at a vmcnt(0).
// Epilogue round-trips C through LDS so Apack stores are coalesced.
// ---------------------------------------------------------------------------
__global__ __launch_bounds__(256) void gemm1_kernel(
        const __bf16* __restrict__ A, const __bf16* __restrict__ Bt,
        const float* __restrict__ bias, __bf16* __restrict__ Apack, int K) {
    __shared__ __align__(16) __bf16 At[128][40];
    __shared__ __align__(16) __bf16 Bl[128][40];
    __shared__ __align__(16) __bf16 Cld[128][136];
    const int t = threadIdx.x;
    const int by = blockIdx.y, bx = blockIdx.x;
    const int m0 = by * 128, n0 = bx * 128;
    const int srow = t >> 2, schunk = (t & 3) * 8;
    const int wave = t >> 6, lane = t & 63;
    const int wrow = (wave >> 1) * 64, wcol = (wave & 1) * 64;
    const int q = lane >> 4, ln = lane & 15;

    // prologue: load k0 = 0 staging chunks into registers
    bf16x8 rA0 = *(const bf16x8*)(A  + (size_t)(m0 + srow)      * K + schunk);
    bf16x8 rA1 = *(const bf16x8*)(A  + (size_t)(m0 + srow + 64) * K + schunk);
    bf16x8 rB0 = *(const bf16x8*)(Bt + (size_t)(n0 + srow)      * K + schunk);
    bf16x8 rB1 = *(const bf16x8*)(Bt + (size_t)(n0 + srow + 64) * K + schunk);

    f32x4 acc[4][4] = {};
    for (int k0 = 0; k0 < K; k0 += 32) {
        __syncthreads();                       // prev iter's ds_reads done
        *(bf16x8*)&At[srow][schunk]      = rA0;
        *(bf16x8*)&At[srow + 64][schunk] = rA1;
        *(bf16x8*)&Bl[srow][schunk]      = rB0;
        *(bf16x8*)&Bl[srow + 64][schunk] = rB1;
        __syncthreads();
        if (k0 + 32 < K) {                     // prefetch next chunk (hides
            int kn = k0 + 32 + schunk;         //  under ds_read+MFMA below)
            rA0 = *(const bf16x8*)(A  + (size_t)(m0 + srow)      * K + kn);
            rA1 = *(const bf16x8*)(A  + (size_t)(m0 + srow + 64) * K + kn);
            rB0 = *(const bf16x8*)(Bt + (size_t)(n0 + srow)      * K + kn);
            rB1 = *(const bf16x8*)(Bt + (size_t)(n0 + srow + 64) * K + kn);
        }
        bf16x8 af[4], bfr[4];
        for (int i = 0; i < 4; i++) af[i]  = *(const bf16x8*)&At[wrow + i * 16 + ln][q * 8];
        for (int i = 0; i < 4; i++) bfr[i] = *(const bf16x8*)&Bl[wcol + i * 16 + ln][q * 8];
        for (int mi = 0; mi < 4; mi++)
            for (int ni = 0; ni < 4; ni++)
                acc[mi][ni] = MFMA16(af[mi], bfr[ni], acc[mi][ni]);
    }
    // bias + leaky -> LDS C tile
    for (int ni = 0; ni < 4; ni++) {
        int gcol = n0 + wcol + ni * 16 + ln;
        float bv = bias[gcol];
        for (int mi = 0; mi < 4; mi++)
            for (int r = 0; r < 4; r++) {
                float v = acc[mi][ni][r] + bv;
                v = v > 0.0f ? v : 0.01f * v;
                Cld[wrow + mi * 16 + q * 4 + r][wcol + ni * 16 + ln] = (__bf16)v;
            }
    }
    __syncthreads();
    // pack out: 32 chunks (pl 0..1, ksl 0..3, mi 0..3), wave w -> c = w+4i
    for (int i = 0; i < 8; i++) {
        int c   = wave + 4 * i;
        int pl  = c >> 4, ksl = (c >> 2) & 3, mi = c & 3;
        int row = pl * 64 + mi * 16 + (lane & 15);
        int col = ksl * 32 + (lane >> 4) * 8;
        bf16x8 v = *(const bf16x8*)&Cld[row][col];
        size_t base = apack_chunk(2 * by + pl, 4 * bx + ksl, mi);
        *(bf16x8*)(Apack + base + lane * 8) = v;
    }
}

// ---------------------------------------------------------------------------
// GEMM2 (persistent 64-col strip, 512 threads = 8 waves, 2 blocks/CU) --
// R4/R8-VERBATIM schedule (measured 199-202 us, spill-free at the
// 64-arch-VGPR cap; do not reorder the epilogue: lc loads -> merged
// label/exp loop -> reduce).  W2 strip staged once fp32->bf16 into
// fragment-major LDS "Bpack" (conflict-free b128; non-temporal loads
// protect Apack's L2 residency).  A frags from L2 with one-k-step
// prefetch.  This schedule is the floor of its resource box (R9-R14).
// ---------------------------------------------------------------------------
__global__ __launch_bounds__(512, 4) void gemm2_kernel(
        const __bf16* __restrict__ Apack, const float* __restrict__ w2,
        const float* __restrict__ b2, const int* __restrict__ labcol,
        float* __restrict__ partial, float* __restrict__ lab, int Mpad) {
    __shared__ __align__(16) __bf16 Bp[64 * 512];   // 64 KB, fragment-major
    const int t = threadIdx.x;
    const int strip = blockIdx.x;
    const int c0 = strip * 64;
    const int branch = (c0 >= V) ? 1 : 0;

    // ---- stage W2 strip fp32 [512][64000] -> Bpack bf16
    {
        const int col = t & 63;
        const int ni = col >> 4, lncol = col & 15;
        const int kb0 = (t >> 6) * 8;
        for (int r = 0; r < 8; r++) {
            int kb = kb0 + r * 64;
            int ks = kb >> 5, qk = (kb >> 3) & 3;
            float v[8];
#pragma unroll
            for (int j = 0; j < 8; j++)
                v[j] = __builtin_nontemporal_load(w2 + (size_t)(kb + j) * N2 + c0 + col);
            bf16x8 o;
#pragma unroll
            for (int j = 0; j < 8; j++) o[j] = (__bf16)v[j];
            *(bf16x8*)&Bp[(size_t)(((ks * 4 + ni) * 64 + qk * 16 + lncol)) * 8] = o;
        }
    }
    __syncthreads();

    const int wave = t >> 6, lane = t & 63;
    const int q = lane >> 4, ln = lane & 15;

    float bvn[4];
#pragma unroll
    for (int ni = 0; ni < 4; ni++) bvn[ni] = b2[c0 + ni * 16 + ln];

    const int npanels = Mpad >> 6;
    for (int p = wave; p < npanels; p += 8) {
        const __bf16* base = Apack + apack_chunk(p, 0, 0) + lane * 8;

        f32x4 acc[4][4] = {};
        bf16x8 afc[4], afn[4];
#pragma unroll
        for (int mi = 0; mi < 4; mi++)
            afc[mi] = *(const bf16x8*)(base + mi * 512);
#pragma unroll 1
        for (int ks = 0; ks < 16; ks++) {
            if (ks < 15) {
#pragma unroll
                for (int mi = 0; mi < 4; mi++)
                    afn[mi] = *(const bf16x8*)(base + (size_t)(ks + 1) * 2048 + mi * 512);
            }
            bf16x8 bf[4];
#pragma unroll
            for (int ni = 0; ni < 4; ni++)
                bf[ni] = *(const bf16x8*)&Bp[(size_t)(ks * 4 + ni) * 512 + lane * 8];
#pragma unroll
            for (int mi = 0; mi < 4; mi++)
#pragma unroll
                for (int ni = 0; ni < 4; ni++)
                    acc[mi][ni] = MFMA16(afc[mi], bf[ni], acc[mi][ni]);
#pragma unroll
            for (int mi = 0; mi < 4; mi++) afc[mi] = afn[mi];
        }

        // ---- epilogue for this panel (R4 order)
        int lc[4][4];
#pragma unroll
        for (int mi = 0; mi < 4; mi++)
#pragma unroll
            for (int r = 0; r < 4; r++)
                lc[mi][r] = labcol[(p * 64 + mi * 16 + q * 4 + r) * 2 + branch];

        float rowsum[4][4];
#pragma unroll
        for (int mi = 0; mi < 4; mi++)
#pragma unroll
            for (int r = 0; r < 4; r++) rowsum[mi][r] = 0.0f;

#pragma unroll
        for (int ni = 0; ni < 4; ni++) {
            const int gcol = c0 + ni * 16 + ln;
            const float bv = bvn[ni];
#pragma unroll
            for (int mi = 0; mi < 4; mi++)
#pragma unroll
                for (int r = 0; r < 4; r++) {
                    float v = acc[mi][ni][r] + bv;
                    rowsum[mi][r] += __expf(v);
                    if (gcol == lc[mi][r]) {
                        int gm = p * 64 + mi * 16 + q * 4 + r;
                        lab[gm * 2 + branch] = v;
                    }
                }
        }
        // reduce over the 16 column-lanes (lane bits 0..3)
#pragma unroll
        for (int mi = 0; mi < 4; mi++)
#pragma unroll
            for (int r = 0; r < 4; r++) {
                float s = rowsum[mi][r];
                s += __shfl_xor(s, 1);
                s += __shfl_xor(s, 2);
                s += __shfl_xor(s, 4);
                s += __shfl_xor(s, 8);
                rowsum[mi][r] = s;
            }
        // per-lane row gather: lane l wants row l = mi*16 + q*4 + r; value
        // lives in lanes with q-src = (l>>2)&3 at register rowsum[l>>4][l&3].
        float mine = 0.0f;
        const int srcl = ((lane >> 2) & 3) * 16;
#pragma unroll
        for (int mi2 = 0; mi2 < 4; mi2++)
#pragma unroll
            for (int r2 = 0; r2 < 4; r2++) {
                float tv = __shfl(rowsum[mi2][r2], srcl);
                if ((lane >> 4) == mi2 && (lane & 3) == r2) mine = tv;
            }
        partial[(size_t)strip * Mpad + p * 64 + lane] = mine;
    }
}

// ---------------------------------------------------------------------------
// Fused final: block per (64-row panel, branch). 4 waves split the branch's
// 500 strips (125 each), coalesced 256 B reads, LDS combine, then wave 0
// computes nll = log(sumexp) - lab, weights, reduces, atomicAdd into out.
// ---------------------------------------------------------------------------
__global__ __launch_bounds__(256) void final_kernel(
        const float* __restrict__ partial, const float* __restrict__ lab,
        float* __restrict__ out, int M, int Mpad) {
    __shared__ float red[4][64];
    const int br = blockIdx.x & 1;
    const int m0 = (blockIdx.x >> 1) * 64;
    const int wave = threadIdx.x >> 6, lane = threadIdx.x & 63;
    const int s0 = br * (NSTRIP / 2) + wave * (NSTRIP / 8);
    float s = 0.0f;
#pragma unroll 5
    for (int i = 0; i < NSTRIP / 8; i++)
        s += partial[(size_t)(s0 + i) * Mpad + m0 + lane];
    red[wave][lane] = s;
    __syncthreads();
    if (wave == 0) {
        float tot = red[0][lane] + red[1][lane] + red[2][lane] + red[3][lane];
        int m = m0 + lane;
        float acc = 0.0f;
        if (m < M)
            acc = (br ? 0.25f : 1.0f) * (logf(tot) - lab[m * 2 + br]);
        acc += __shfl_xor(acc, 32);
        acc += __shfl_xor(acc, 16);
        acc += __shfl_xor(acc, 8);
        acc += __shfl_xor(acc, 4);
        acc += __shfl_xor(acc, 2);
        acc += __shfl_xor(acc, 1);
        if (lane == 0) atomicAdd(out, acc / (float)(2 * M));
    }
}

// ---------------------------------------------------------------------------
extern "C" void kernel_launch(void* const* d_in, const int* in_sizes, int n_in,
                              void* d_out, int out_size, void* d_ws, size_t ws_size,
                              hipStream_t stream) {
    const float* fwd = (const float*)d_in[0];
    const float* bwd = (const float*)d_in[1];
    const int*   seq = (const int*)d_in[2];
    const int*   fi  = (const int*)d_in[3];
    const int*   bi  = (const int*)d_in[4];
    const float* w1  = (const float*)d_in[5];
    const float* b1  = (const float*)d_in[6];
    const float* w2  = (const float*)d_in[7];
    const float* b2  = (const float*)d_in[8];
    float* out = (float*)d_out;

    const int N    = in_sizes[3];              // 1303
    const int M    = Bsz * N;                  // 2606
    const int Mpad = ((M + 255) / 256) * 256;  // 2816

    // workspace layout (16B-aligned slices)
    char* ws = (char*)d_ws;
    __bf16* A1    = (__bf16*)(ws);                                   // Mpad*1024
    __bf16* W1T   = (__bf16*)(ws + (size_t)Mpad * K1 * 2);           // 512*1024
    __bf16* Apack = (__bf16*)((char*)W1T + (size_t)N1 * K1 * 2);     // Mpad*512
    float*  partial = (float*)((char*)Apack + (size_t)Mpad * N1 * 2);// NSTRIP*Mpad
    float*  lab     = (float*)((char*)partial + (size_t)NSTRIP * Mpad * 4); // Mpad*2
    int*    labcol  = (int*)((char*)lab + (size_t)Mpad * 2 * 4);     // Mpad*2

    // 1. fused prep: gather+cast (+labcol interleaved), w1 transpose,
    //    and out zeroing (no separate memset dispatch)
    {
        int G1 = Mpad * (K1 / 8) / 256;        // gather blocks
        prep_kernel<<<G1 + 128, 256, 0, stream>>>(
            fwd, bwd, fi, bi, seq, w1, A1, W1T, labcol, out, N, M, Mpad, G1);
    }
    // 2. GEMM1 -> Apack (fragment-major H), register-dbuf staging
    gemm1_kernel<<<dim3(N1 / 128, Mpad / 128), 256, 0, stream>>>(A1, W1T, b1, Apack, K1);
    // 3. GEMM2 persistent strips -> per-strip partial rowsums + labels
    gemm2_kernel<<<NSTRIP, 512, 0, stream>>>(Apack, w2, b2, labcol, partial, lab, Mpad);
    // 4. fused final: strip-reduce + NLL + weighted mean -> out
    final_kernel<<<(Mpad / 64) * 2, 256, 0, stream>>>(partial, lab, out, M, Mpad);
}